// Round 1
// baseline (1242.331 us; speedup 1.0000x reference)
//
#include <hip/hip_runtime.h>
#include <math.h>

#define EPSF 1e-15f
#define MAX_ATANH (1.0f - 1e-5f)
#define ATT 16

__device__ __forceinline__ float geluf(float x) {
    // exact GELU: x * 0.5 * (1 + erf(x / sqrt(2)))
    return 0.5f * x * (1.0f + erff(x * 0.70710678118654752f));
}

// Per-edge: gather endpoints, hyperbolic log-map, MLP score, exp, atomic scatter.
__global__ void edge_pass(const float2* __restrict__ x,
                          const float* __restrict__ W1,   // [2][16]
                          const float* __restrict__ b1,   // [16]
                          const float* __restrict__ W2,   // [16]
                          const int* __restrict__ row,
                          const int* __restrict__ col,
                          float* __restrict__ den,
                          float* __restrict__ accx,
                          float* __restrict__ accy,
                          int E) {
    const int stride = gridDim.x * blockDim.x;
    for (int e = blockIdx.x * blockDim.x + threadIdx.x; e < E; e += stride) {
        const int r = row[e];
        const int c = col[e];
        const float2 xi = x[r];
        const float2 xj = x[c];

        // sub = mobius_add(-xi, xj), c = 1
        const float ax = -xi.x, ay = -xi.y;
        const float bx = xj.x,  by = xj.y;
        const float a2 = ax * ax + ay * ay;
        const float b2 = bx * bx + by * by;
        const float ab = ax * bx + ay * by;
        const float ca = 1.0f + 2.0f * ab + b2;   // coef on a
        const float cb = 1.0f - a2;               // coef on b
        const float dn = fmaxf(1.0f + 2.0f * ab + a2 * b2, EPSF);
        const float subx = (ca * ax + cb * bx) / dn;
        const float suby = (ca * ay + cb * by) / dn;

        // log map: v = (2/lam) * atanh(min(n, MAX)) * sub / n ; 2/lam = max(1-|xi|^2, EPS)
        const float n = fmaxf(sqrtf(subx * subx + suby * suby), EPSF);
        const float M = fmaxf(1.0f - (xi.x * xi.x + xi.y * xi.y), EPSF);
        const float scl = M * atanhf(fminf(n, MAX_ATANH)) / n;
        const float vx = scl * subx;
        const float vy = scl * suby;

        // MLP scorer: gelu(v @ W1 + b1) @ W2
        float s = 0.0f;
        #pragma unroll
        for (int k = 0; k < ATT; ++k) {
            const float hk = geluf(fmaf(vx, W1[k], fmaf(vy, W1[ATT + k], b1[k])));
            s = fmaf(hk, W2[k], s);
        }

        // max-free softmax numerator (|s| << 88, exp is safe in f32)
        const float ee = expf(s);
        atomicAdd(&den[r],  ee);
        atomicAdd(&accx[r], ee * vx);
        atomicAdd(&accy[r], ee * vy);
    }
}

// Per-node: normalize, depth mixer (scale+rotation), exp-map update.
__global__ void node_pass(const float2* __restrict__ x,
                          const float* __restrict__ den,
                          const float* __restrict__ accx,
                          const float* __restrict__ accy,
                          const int* __restrict__ depth,
                          const float* __restrict__ depth_scale,
                          const float* __restrict__ depth_theta,
                          const float* __restrict__ eta_p,
                          float2* __restrict__ out,
                          int V) {
    const float eta = eta_p[0];
    const int stride = gridDim.x * blockDim.x;
    for (int v = blockIdx.x * blockDim.x + threadIdx.x; v < V; v += stride) {
        const float dv = fmaxf(den[v], EPSF);
        const float mx = accx[v] / dv;
        const float my = accy[v] / dv;

        const int d = min(depth[v], 511);
        const float k   = depth_scale[d];
        const float ang = depth_theta[d];
        const float cs = cosf(ang), sn = sinf(ang);
        const float m0 = eta * (k * (cs * mx - sn * my));
        const float m1 = eta * (k * (sn * mx + cs * my));

        const float2 xi = x[v];

        // exp_map_x(xi, m): n, lam, tanh(0.5*lam*n) * m/n
        const float n = fmaxf(sqrtf(m0 * m0 + m1 * m1), EPSF);
        const float M = fmaxf(1.0f - (xi.x * xi.x + xi.y * xi.y), EPSF);
        const float t = tanhf(n / M);          // 0.5 * lam * n = n / M
        const float bx = t * m0 / n;
        const float by = t * m1 / n;

        // mobius_add(xi, b)
        const float a2 = xi.x * xi.x + xi.y * xi.y;
        const float b2 = bx * bx + by * by;
        const float ab = xi.x * bx + xi.y * by;
        const float ca = 1.0f + 2.0f * ab + b2;
        const float cb = 1.0f - a2;
        const float dn = fmaxf(1.0f + 2.0f * ab + a2 * b2, EPSF);

        out[v] = make_float2((ca * xi.x + cb * bx) / dn,
                             (ca * xi.y + cb * by) / dn);
    }
}

extern "C" void kernel_launch(void* const* d_in, const int* in_sizes, int n_in,
                              void* d_out, int out_size, void* d_ws, size_t ws_size,
                              hipStream_t stream) {
    const float2* x          = (const float2*)d_in[0];
    const float*  W1         = (const float*)d_in[1];
    const float*  b1         = (const float*)d_in[2];
    const float*  W2         = (const float*)d_in[3];
    const float*  eta        = (const float*)d_in[4];
    const float*  dscale     = (const float*)d_in[5];
    const float*  dtheta     = (const float*)d_in[6];
    const int*    edge_index = (const int*)d_in[7];
    const int*    depth      = (const int*)d_in[8];

    const int V = in_sizes[0] / 2;
    const int E = in_sizes[7] / 2;

    const int* row = edge_index;
    const int* col = edge_index + E;

    float* den  = (float*)d_ws;
    float* accx = den + V;
    float* accy = accx + V;

    // zero the accumulators (harness does not re-poison between replays)
    hipMemsetAsync(d_ws, 0, (size_t)3 * V * sizeof(float), stream);

    const int block = 256;
    const int gridE = 2048;                      // grid-stride, ~16 edges/thread
    const int gridV = min((V + block - 1) / block, 2048);

    edge_pass<<<gridE, block, 0, stream>>>(x, W1, b1, W2, row, col,
                                           den, accx, accy, E);
    node_pass<<<gridV, block, 0, stream>>>(x, den, accx, accy, depth,
                                           dscale, dtheta, eta,
                                           (float2*)d_out, V);
}